// Round 14
// baseline (430.467 us; speedup 1.0000x reference)
//
#include <hip/hip_runtime.h>
#include <hip/hip_bf16.h>
#include <math.h>

// CRF NLL on MI355X — round 14. Exactly r12 (best: 137us fwd, absmax 0.0) with
// ONE change: the emission prefetch loads are VOLATILE.
// r12 diagnosis: pipeline needs ~230 VGPR for A+EX+R0+R1; VGPR_Count=132 =>
// scheduler sank each LOADBLK to just before its consuming EXPBLK (legal:
// loads are rematerializable/sinkable) => raw L2/HBM latency every 4 steps,
// the dominant stall at 1 wave/CU. volatile loads: cannot be sunk, cannot be
// re-executed by regalloc (dest regs MUST stay live), but do NOT force a wait
// at issue — s_waitcnt lands at the consumer ~8 steps later. r13's membar
// variant is reverted (it serialized the scheduler; regressed).

#define NTAGS   48
#define NST     50
#define START_S 48
#define STOP_S  49
#define BATCH   1024
#define TLEN    512

typedef short  bf16x8 __attribute__((ext_vector_type(8)));
typedef float  f32x4  __attribute__((ext_vector_type(4)));

union B4 { unsigned u[4]; short s[8]; bf16x8 v; };

__device__ __forceinline__ short to_bf16(float f) {     // RNE, pure C (init paths)
    unsigned u = __float_as_uint(f);
    unsigned r = ((u >> 16) & 1u) + 0x7FFFu;
    return (short)((u + r) >> 16);
}

__device__ __forceinline__ unsigned pk2(float lo, float hi) {  // RNE pair pack
    float2 f; f.x = lo; f.y = hi;
    __hip_bfloat162 h = __float22bfloat162_rn(f);
    union { __hip_bfloat162 h; unsigned u; } cvt; cvt.h = h;
    return cvt.u;                                   // low16 = lo, high16 = hi
}

__device__ __forceinline__ float wave_sum(float v) {
#pragma unroll
    for (int off = 32; off >= 1; off >>= 1)
        v += __shfl_xor(v, off, 64);
    return v;
}

// one recurrence step; X0..X2 = PRE-EXP'D emissions for this t.
// MODE: 0 = normal, 1 = PREP (issue renorm bpermute), 2 = APPLY (use it).
template<int MODE, int LAST>
__device__ __forceinline__ void crf_step(const bf16x8 (&A)[3][2],
    bf16x8 &B0, bf16x8 &B1,
    const f32x4 &X0, const f32x4 &X1, const f32x4 &X2,
    f32x4 &p0, f32x4 &p1, f32x4 &p2, float &Clog, int bp_addr, int &rbp)
{
    const f32x4 z = {0.f, 0.f, 0.f, 0.f};
    f32x4 a0 = __builtin_amdgcn_mfma_f32_16x16x32_bf16(A[0][0], B0, z, 0, 0, 0);
    a0 = __builtin_amdgcn_mfma_f32_16x16x32_bf16(A[0][1], B1, a0, 0, 0, 0);
    f32x4 a1 = __builtin_amdgcn_mfma_f32_16x16x32_bf16(A[1][0], B0, z, 0, 0, 0);
    a1 = __builtin_amdgcn_mfma_f32_16x16x32_bf16(A[1][1], B1, a1, 0, 0, 0);
    f32x4 a2 = __builtin_amdgcn_mfma_f32_16x16x32_bf16(A[2][0], B0, z, 0, 0, 0);
    a2 = __builtin_amdgcn_mfma_f32_16x16x32_bf16(A[2][1], B1, a2, 0, 0, 0);

    p0[0] = a0[0] * X0[0];  p0[1] = a0[1] * X0[1];
    p0[2] = a0[2] * X0[2];  p0[3] = a0[3] * X0[3];
    p1[0] = a1[0] * X1[0];  p1[1] = a1[1] * X1[1];
    p1[2] = a1[2] * X1[2];  p1[3] = a1[3] * X1[3];
    p2[0] = a2[0] * X2[0];  p2[1] = a2[1] * X2[1];
    p2[2] = a2[2] * X2[2];  p2[3] = a2[3] * X2[3];

    if (MODE == 2) {        // APPLY: rbp captured by last step's PREP
        int ex = ((rbp >> 23) & 255) - 127;
        ex = ex > 126 ? 126 : (ex < -126 ? -126 : ex);       // sc finite > 0
        float sc = __uint_as_float((unsigned)(127 - ex) << 23);  // 2^-ex, exact
        p0 *= sc; p1 *= sc; p2 *= sc;
        Clog += (float)ex * 0.69314718055994531f;
    }
    if (MODE == 1) {        // PREP: issue bpermute of state-0 (lane g=0 of col c)
        rbp = __builtin_amdgcn_ds_bpermute(bp_addr, __float_as_int(p0[0]));
    }

    if (!LAST) {            // C -> next B: lane-local renames, packed cvt
        B4 nb0;
        nb0.u[0] = pk2(p0[0], p0[1]);  nb0.u[1] = pk2(p0[2], p0[3]);
        nb0.u[2] = pk2(p1[0], p1[1]);  nb0.u[3] = pk2(p1[2], p1[3]);
        B0 = nb0.v;
        B4 nb1;
        nb1.u[0] = pk2(p2[0], p2[1]);  nb1.u[1] = pk2(p2[2], p2[3]);
        nb1.u[2] = 0u;                 nb1.u[3] = 0u;
        B1 = nb1.v;
    }
}

// VOLATILE prefetch loads: not sinkable, not re-executable, no wait at issue.
#define LOADBLK(R, T)                                                        \
    _Pragma("unroll") for (int u2 = 0; u2 < 4; ++u2) {                       \
        _Pragma("unroll") for (int mt = 0; mt < 3; ++mt)                     \
            R[u2][mt] = *(const volatile f32x4*)(emg + (size_t)((T) + u2) * NTAGS + 16 * mt); \
    }

#define LOADBLK_C(R, T)                                                      \
    _Pragma("unroll") for (int u2 = 0; u2 < 4; ++u2) {                       \
        int tu = (T) + u2; tu = tu > 511 ? 511 : tu;                         \
        _Pragma("unroll") for (int mt = 0; mt < 3; ++mt)                     \
            R[u2][mt] = *(const volatile f32x4*)(emg + (size_t)tu * NTAGS + 16 * mt); \
    }

#define EXPBLK(X, R)                                                         \
    _Pragma("unroll") for (int u2 = 0; u2 < 4; ++u2)                         \
        _Pragma("unroll") for (int mt = 0; mt < 3; ++mt)                     \
            _Pragma("unroll") for (int r = 0; r < 4; ++r)                    \
                X[u2][mt][r] = __expf(R[u2][mt][r]);

#define BLK4(X)                                                              \
    crf_step<0,0>(A, B0, B1, X[0][0], X[0][1], X[0][2], p0, p1, p2, Clog, bp_addr, rbp); \
    crf_step<0,0>(A, B0, B1, X[1][0], X[1][1], X[1][2], p0, p1, p2, Clog, bp_addr, rbp); \
    crf_step<1,0>(A, B0, B1, X[2][0], X[2][1], X[2][2], p0, p1, p2, Clog, bp_addr, rbp); \
    crf_step<2,0>(A, B0, B1, X[3][0], X[3][1], X[3][2], p0, p1, p2, Clog, bp_addr, rbp);

__global__ __launch_bounds__(64)
__attribute__((amdgpu_waves_per_eu(1, 1)))
void crf_forward_mfma(const float* __restrict__ emissions,  // [B, T, 48]
                      const float* __restrict__ trans,      // [50, 50]
                      float*       __restrict__ logz_out)   // [B]
{
    const int l = threadIdx.x;
    const int g = l >> 4;
    const int c = l & 15;
    const int brow = blockIdx.x * 16 + c;

    // ---- A[mt][kt]: elem e holds M[tau(kt,g,e)][16mt+c], tau = 16*(2kt+(e>>2))+4g+(e&3)
    bf16x8 A[3][2];
#pragma unroll
    for (int mt = 0; mt < 3; ++mt)
#pragma unroll
        for (int kt = 0; kt < 2; ++kt) {
            B4 u;
#pragma unroll
            for (int e = 0; e < 8; ++e) {
                const int sk = 16 * (2 * kt + (e >> 2)) + 4 * g + (e & 3);
                const int m  = 16 * mt + c;
                const float f = (sk < NTAGS) ? __expf(trans[sk * NST + m]) : 0.0f;
                u.s[e] = to_bf16(f);
            }
            A[mt][kt] = u.v;
        }
    asm volatile("" : "+v"(A[0][0]), "+v"(A[0][1]), "+v"(A[1][0]),
                      "+v"(A[1][1]), "+v"(A[2][0]), "+v"(A[2][1]));

    const float* emc = emissions + (size_t)brow * (TLEN * NTAGS);
    const float* emg = emc + 4 * g;

    // ---- B init at t=0 in tau layout: q0_i = exp(trans[START][i] + em0_i)
    bf16x8 B0, B1;
    {
        f32x4 i0 = *(const f32x4*)(emc +      4 * g);
        f32x4 i1 = *(const f32x4*)(emc + 16 + 4 * g);
        f32x4 i2 = *(const f32x4*)(emc + 32 + 4 * g);
        B4 nb0, nb1;
#pragma unroll
        for (int r = 0; r < 4; ++r) {
            nb0.s[r]     = to_bf16(__expf(trans[START_S * NST +      4 * g + r] + i0[r]));
            nb0.s[4 + r] = to_bf16(__expf(trans[START_S * NST + 16 + 4 * g + r] + i1[r]));
            nb1.s[r]     = to_bf16(__expf(trans[START_S * NST + 32 + 4 * g + r] + i2[r]));
        }
        nb1.u[2] = 0u;  nb1.u[3] = 0u;
        B0 = nb0.v;  B1 = nb1.v;
    }

    const int bp_addr = c << 2;
    f32x4 p0, p1, p2;
    float Clog = 0.0f;
    int rbp = __float_as_int(1.0f);

    // ---- 8-step-deep pipeline: EX = exp'd current block; R0/R1 raw ahead
    f32x4 EX[4][3], R0[4][3], R1[4][3];
    {
        f32x4 T0[4][3];
        LOADBLK(T0, 1)
        LOADBLK(R0, 5)
        LOADBLK(R1, 9)
        EXPBLK(EX, T0)
    }

    int t = 1;
    for (int d = 0; d < 63; ++d) {                 // 2 blocks/iter, t = 1..504
        BLK4(EX)                                   // steps t..t+3
        EXPBLK(EX, R0)                             // EX <- t+4..t+7 (loads 8 steps old)
        LOADBLK_C(R0, t + 12)
        BLK4(EX)                                   // steps t+4..t+7
        EXPBLK(EX, R1)                             // EX <- t+8..t+11
        LOADBLK_C(R1, t + 16)
        t += 8;
    }
    // t == 505: EX = exp(505..508); R0 = raw(509,510,511,511)
    BLK4(EX)
    f32x4 XT[3][3];
#pragma unroll
    for (int u2 = 0; u2 < 3; ++u2)
#pragma unroll
        for (int mt = 0; mt < 3; ++mt)
#pragma unroll
            for (int r = 0; r < 4; ++r)
                XT[u2][mt][r] = __expf(R0[u2][mt][r]);
    crf_step<0,0>(A, B0, B1, XT[0][0], XT[0][1], XT[0][2], p0, p1, p2, Clog, bp_addr, rbp);
    crf_step<0,0>(A, B0, B1, XT[1][0], XT[1][1], XT[1][2], p0, p1, p2, Clog, bp_addr, rbp);
    crf_step<0,1>(A, B0, B1, XT[2][0], XT[2][1], XT[2][2], p0, p1, p2, Clog, bp_addr, rbp);

    // ---- logz[col c] = Clog + log( sum_j p_j * exp(trans[j][STOP]) )
    float part = 0.0f;
#pragma unroll
    for (int r = 0; r < 4; ++r) {
        part += p0[r] * __expf(trans[(     4 * g + r) * NST + STOP_S]);
        part += p1[r] * __expf(trans[(16 + 4 * g + r) * NST + STOP_S]);
        part += p2[r] * __expf(trans[(32 + 4 * g + r) * NST + STOP_S]);
    }
    part += __shfl_xor(part, 16, 64);   // reduce over the column's 4 g-lanes
    part += __shfl_xor(part, 32, 64);
    if (l < 16) logz_out[blockIdx.x * 16 + l] = Clog + __logf(part);
}

__global__ __launch_bounds__(64)
void crf_gold_kernel(const float* __restrict__ emissions,
                     const int*   __restrict__ tags,
                     const float* __restrict__ trans,
                     float*       __restrict__ gold_out)
{
    const int b    = blockIdx.x;
    const int lane = threadIdx.x;
    const float* em  = emissions + (size_t)b * TLEN * NTAGS;
    const int*   tbp = tags + (size_t)b * TLEN;
    float gacc = 0.0f;
#pragma unroll
    for (int k = 0; k < TLEN / 64; ++k) {
        const int tt  = k * 64 + lane;
        const int tag = tbp[tt];
        gacc += em[(size_t)tt * NTAGS + tag];
        if (tt >= 1) gacc += trans[tbp[tt - 1] * NST + tag];
    }
    gacc = wave_sum(gacc);
    if (lane == 0)
        gold_out[b] = gacc + trans[START_S * NST + tbp[0]]
                           + trans[tbp[TLEN - 1] * NST + STOP_S];
}

__global__ __launch_bounds__(256)
void crf_reduce_kernel(const float* __restrict__ logz,
                       const float* __restrict__ gold,
                       float*       __restrict__ out)
{
    __shared__ float buf[4];
    float s = 0.0f;
    for (int i = threadIdx.x; i < BATCH; i += 256) s += logz[i] - gold[i];
    s = wave_sum(s);
    const int wid = threadIdx.x >> 6;
    if ((threadIdx.x & 63) == 0) buf[wid] = s;
    __syncthreads();
    if (threadIdx.x == 0) {
        const float tot = (buf[0] + buf[1]) + (buf[2] + buf[3]);
        const float nll = tot / (float)BATCH;
        const float h_max = logf((float)NTAGS);
        out[0] = 0.9f * nll + 0.1f * h_max;
    }
}

extern "C" void kernel_launch(void* const* d_in, const int* in_sizes, int n_in,
                              void* d_out, int out_size, void* d_ws, size_t ws_size,
                              hipStream_t stream)
{
    const float* emissions = (const float*)d_in[0];
    const int*   tags      = (const int*)d_in[1];
    // d_in[2] = mask: all-ones; ignored
    const float* trans     = (const float*)d_in[3];

    if (ws_size < 2 * BATCH * sizeof(float)) return;
    float* logz = (float*)d_ws;
    float* gold = logz + BATCH;

    crf_forward_mfma<<<BATCH / 16, 64, 0, stream>>>(emissions, trans, logz);
    crf_gold_kernel<<<BATCH, 64, 0, stream>>>(emissions, tags, trans, gold);
    crf_reduce_kernel<<<1, 256, 0, stream>>>(logz, gold, (float*)d_out);
}

// Round 15
// 109.572 us; speedup vs baseline: 3.9286x; 3.9286x over previous
//
#include <hip/hip_runtime.h>
#include <hip/hip_bf16.h>
#include <math.h>

// CRF NLL on MI355X — round 15: forward/backward midpoint split.
// r12-r14 established the per-step latency (~645 cyc) can't be cut at source
// level; so cut the CHAIN LENGTH: logZ = u_255 . q_255 with
//   forward  q_t = D_{e_t} W^T q_{t-1}   (t = 1..255, init with e_0 + START)
//   backward u_{t-1} = W (e_t o u_t)     (t = 511..256, init u_511 = exp(T[:,STOP]))
// Two independent 256-step chains, one per wave, same block; combine via LDS.
// Same tau layout / pk2 pack / exact pow2 PREP-APPLY renorm as r12 (absmax 0).
// Extra: the two K-tile MFMAs are independent (z-init + f32 add), removing one
// MFMA latency from the step chain.

#define NTAGS   48
#define NST     50
#define START_S 48
#define STOP_S  49
#define BATCH   1024
#define TLEN    512

typedef short  bf16x8 __attribute__((ext_vector_type(8)));
typedef float  f32x4  __attribute__((ext_vector_type(4)));

union B4 { unsigned u[4]; short s[8]; bf16x8 v; };

__device__ __forceinline__ short to_bf16(float f) {     // RNE, pure C
    unsigned u = __float_as_uint(f);
    unsigned r = ((u >> 16) & 1u) + 0x7FFFu;
    return (short)((u + r) >> 16);
}

__device__ __forceinline__ unsigned pk2(float lo, float hi) {  // RNE pair pack
    float2 f; f.x = lo; f.y = hi;
    __hip_bfloat162 h = __float22bfloat162_rn(f);
    union { __hip_bfloat162 h; unsigned u; } cvt; cvt.h = h;
    return cvt.u;
}

__device__ __forceinline__ float wave_sum(float v) {
#pragma unroll
    for (int off = 32; off >= 1; off >>= 1)
        v += __shfl_xor(v, off, 64);
    return v;
}

#define RENORM_APPLY                                                     \
    {   int ex = ((rbp >> 23) & 255) - 127;                              \
        ex = ex > 126 ? 126 : (ex < -126 ? -126 : ex);                   \
        float sc = __uint_as_float((unsigned)(127 - ex) << 23);          \
        p0 *= sc; p1 *= sc; p2 *= sc;                                    \
        Clog += (float)ex * 0.69314718055994531f; }

// ---- forward step: p=q_t out; B built from p unless LAST. MODE:1=PREP 2=APPLY
template<int MODE, int LAST>
__device__ __forceinline__ void fwd_step(const bf16x8 (&A)[3][2],
    bf16x8 &B0, bf16x8 &B1,
    const f32x4 &X0, const f32x4 &X1, const f32x4 &X2,
    f32x4 &p0, f32x4 &p1, f32x4 &p2, float &Clog, int bp_addr, int &rbp)
{
    const f32x4 z = {0.f, 0.f, 0.f, 0.f};
    f32x4 a0a = __builtin_amdgcn_mfma_f32_16x16x32_bf16(A[0][0], B0, z, 0, 0, 0);
    f32x4 a0b = __builtin_amdgcn_mfma_f32_16x16x32_bf16(A[0][1], B1, z, 0, 0, 0);
    f32x4 a1a = __builtin_amdgcn_mfma_f32_16x16x32_bf16(A[1][0], B0, z, 0, 0, 0);
    f32x4 a1b = __builtin_amdgcn_mfma_f32_16x16x32_bf16(A[1][1], B1, z, 0, 0, 0);
    f32x4 a2a = __builtin_amdgcn_mfma_f32_16x16x32_bf16(A[2][0], B0, z, 0, 0, 0);
    f32x4 a2b = __builtin_amdgcn_mfma_f32_16x16x32_bf16(A[2][1], B1, z, 0, 0, 0);
    p0 = (a0a + a0b) * X0;
    p1 = (a1a + a1b) * X1;
    p2 = (a2a + a2b) * X2;
    if (MODE == 2) RENORM_APPLY
    if (MODE == 1) rbp = __builtin_amdgcn_ds_bpermute(bp_addr, __float_as_int(p0[0]));
    if (!LAST) {
        B4 nb0;
        nb0.u[0] = pk2(p0[0], p0[1]);  nb0.u[1] = pk2(p0[2], p0[3]);
        nb0.u[2] = pk2(p1[0], p1[1]);  nb0.u[3] = pk2(p1[2], p1[3]);
        B0 = nb0.v;
        B4 nb1;
        nb1.u[0] = pk2(p2[0], p2[1]);  nb1.u[1] = pk2(p2[2], p2[3]);
        nb1.u[2] = 0u;                 nb1.u[3] = 0u;
        B1 = nb1.v;
    }
}

// ---- backward step: p = u_t in, u_{t-1} out.  h = p o X; pack; MFMA.
template<int MODE>
__device__ __forceinline__ void bwd_step(const bf16x8 (&A)[3][2],
    const f32x4 &X0, const f32x4 &X1, const f32x4 &X2,
    f32x4 &p0, f32x4 &p1, f32x4 &p2, float &Clog, int bp_addr, int &rbp)
{
    f32x4 h0 = p0 * X0, h1 = p1 * X1, h2 = p2 * X2;
    B4 nb0;
    nb0.u[0] = pk2(h0[0], h0[1]);  nb0.u[1] = pk2(h0[2], h0[3]);
    nb0.u[2] = pk2(h1[0], h1[1]);  nb0.u[3] = pk2(h1[2], h1[3]);
    B4 nb1;
    nb1.u[0] = pk2(h2[0], h2[1]);  nb1.u[1] = pk2(h2[2], h2[3]);
    nb1.u[2] = 0u;                 nb1.u[3] = 0u;
    const bf16x8 B0 = nb0.v, B1 = nb1.v;
    const f32x4 z = {0.f, 0.f, 0.f, 0.f};
    f32x4 a0a = __builtin_amdgcn_mfma_f32_16x16x32_bf16(A[0][0], B0, z, 0, 0, 0);
    f32x4 a0b = __builtin_amdgcn_mfma_f32_16x16x32_bf16(A[0][1], B1, z, 0, 0, 0);
    f32x4 a1a = __builtin_amdgcn_mfma_f32_16x16x32_bf16(A[1][0], B0, z, 0, 0, 0);
    f32x4 a1b = __builtin_amdgcn_mfma_f32_16x16x32_bf16(A[1][1], B1, z, 0, 0, 0);
    f32x4 a2a = __builtin_amdgcn_mfma_f32_16x16x32_bf16(A[2][0], B0, z, 0, 0, 0);
    f32x4 a2b = __builtin_amdgcn_mfma_f32_16x16x32_bf16(A[2][1], B1, z, 0, 0, 0);
    p0 = a0a + a0b;  p1 = a1a + a1b;  p2 = a2a + a2b;
    if (MODE == 2) RENORM_APPLY
    if (MODE == 1) rbp = __builtin_amdgcn_ds_bpermute(bp_addr, __float_as_int(p0[0]));
}

#define LOADBLK(R, T)                                                        \
    _Pragma("unroll") for (int u2 = 0; u2 < 4; ++u2) {                       \
        _Pragma("unroll") for (int mt = 0; mt < 3; ++mt)                     \
            R[u2][mt] = *(const f32x4*)(emg + (size_t)((T) + u2) * NTAGS + 16 * mt); \
    }
#define LOADBLKD(R, T)                                                       \
    _Pragma("unroll") for (int u2 = 0; u2 < 4; ++u2) {                       \
        _Pragma("unroll") for (int mt = 0; mt < 3; ++mt)                     \
            R[u2][mt] = *(const f32x4*)(emg + (size_t)((T) - u2) * NTAGS + 16 * mt); \
    }
#define EXPBLK(X, R)                                                         \
    _Pragma("unroll") for (int u2 = 0; u2 < 4; ++u2)                         \
        _Pragma("unroll") for (int mt = 0; mt < 3; ++mt)                     \
            _Pragma("unroll") for (int r = 0; r < 4; ++r)                    \
                X[u2][mt][r] = __expf(R[u2][mt][r]);

#define FBLK4(X)                                                             \
    fwd_step<0,0>(A, B0, B1, X[0][0], X[0][1], X[0][2], p0, p1, p2, Clog, bp_addr, rbp); \
    fwd_step<0,0>(A, B0, B1, X[1][0], X[1][1], X[1][2], p0, p1, p2, Clog, bp_addr, rbp); \
    fwd_step<1,0>(A, B0, B1, X[2][0], X[2][1], X[2][2], p0, p1, p2, Clog, bp_addr, rbp); \
    fwd_step<2,0>(A, B0, B1, X[3][0], X[3][1], X[3][2], p0, p1, p2, Clog, bp_addr, rbp);

#define BBLK4(X)                                                             \
    bwd_step<0>(A, X[0][0], X[0][1], X[0][2], p0, p1, p2, Clog, bp_addr, rbp); \
    bwd_step<0>(A, X[1][0], X[1][1], X[1][2], p0, p1, p2, Clog, bp_addr, rbp); \
    bwd_step<1>(A, X[2][0], X[2][1], X[2][2], p0, p1, p2, Clog, bp_addr, rbp); \
    bwd_step<2>(A, X[3][0], X[3][1], X[3][2], p0, p1, p2, Clog, bp_addr, rbp);

__global__ __launch_bounds__(128)
__attribute__((amdgpu_waves_per_eu(1, 1)))
void crf_fwdbwd(const float* __restrict__ emissions,  // [B, T, 48]
                const float* __restrict__ trans,      // [50, 50]
                float*       __restrict__ logz_out)   // [B]
{
    __shared__ float xch[64 * 12 + 16];
    const int wid = threadIdx.x >> 6;    // 0 = forward, 1 = backward
    const int l = threadIdx.x & 63;
    const int g = l >> 4;
    const int c = l & 15;
    const int brow = blockIdx.x * 16 + c;

    // ---- A fragments. fwd: A(m=j_out, k=i_in) = trans[i][j] = trans[sk*NST+m]
    //      bwd: A(m=i_out, k=j_in) = trans[i][j] = trans[m*NST+sk]
    bf16x8 A[3][2];
#pragma unroll
    for (int mt = 0; mt < 3; ++mt)
#pragma unroll
        for (int kt = 0; kt < 2; ++kt) {
            B4 u;
#pragma unroll
            for (int e = 0; e < 8; ++e) {
                const int sk = 16 * (2 * kt + (e >> 2)) + 4 * g + (e & 3);
                const int m  = 16 * mt + c;
                float f = 0.0f;
                if (sk < NTAGS)
                    f = __expf(wid == 0 ? trans[sk * NST + m] : trans[m * NST + sk]);
                u.s[e] = to_bf16(f);
            }
            A[mt][kt] = u.v;
        }
    asm volatile("" : "+v"(A[0][0]), "+v"(A[0][1]), "+v"(A[1][0]),
                      "+v"(A[1][1]), "+v"(A[2][0]), "+v"(A[2][1]));

    const float* emc = emissions + (size_t)brow * (TLEN * NTAGS);
    const float* emg = emc + 4 * g;

    const int bp_addr = c << 2;
    f32x4 p0, p1, p2;
    float Clog = 0.0f;
    int rbp = __float_as_int(1.0f);
    f32x4 EX[4][3], R0[4][3], R1[4][3];

    if (wid == 0) {
        // ======== FORWARD: init t=0, steps t=1..255 -> q_255 ========
        bf16x8 B0, B1;
        {
            f32x4 i0 = *(const f32x4*)(emc +      4 * g);
            f32x4 i1 = *(const f32x4*)(emc + 16 + 4 * g);
            f32x4 i2 = *(const f32x4*)(emc + 32 + 4 * g);
            B4 nb0, nb1;
#pragma unroll
            for (int r = 0; r < 4; ++r) {
                nb0.s[r]     = to_bf16(__expf(trans[START_S * NST +      4 * g + r] + i0[r]));
                nb0.s[4 + r] = to_bf16(__expf(trans[START_S * NST + 16 + 4 * g + r] + i1[r]));
                nb1.s[r]     = to_bf16(__expf(trans[START_S * NST + 32 + 4 * g + r] + i2[r]));
            }
            nb1.u[2] = 0u;  nb1.u[3] = 0u;
            B0 = nb0.v;  B1 = nb1.v;
        }
        {
            f32x4 T0[4][3];
            LOADBLK(T0, 1)
            LOADBLK(R0, 5)
            LOADBLK(R1, 9)
            EXPBLK(EX, T0)
        }
        int t = 1;
        for (int d = 0; d < 31; ++d) {             // t = 1..248
            FBLK4(EX)
            EXPBLK(EX, R0)
            LOADBLK(R0, t + 12)
            FBLK4(EX)
            EXPBLK(EX, R1)
            LOADBLK(R1, t + 16)
            t += 8;
        }
        // t==249: EX=exp(249..252); R0=raw(253..256)
        FBLK4(EX)
        f32x4 XT[3][3];
#pragma unroll
        for (int u2 = 0; u2 < 3; ++u2)
#pragma unroll
            for (int mt = 0; mt < 3; ++mt)
#pragma unroll
                for (int r = 0; r < 4; ++r)
                    XT[u2][mt][r] = __expf(R0[u2][mt][r]);
        fwd_step<0,0>(A, B0, B1, XT[0][0], XT[0][1], XT[0][2], p0, p1, p2, Clog, bp_addr, rbp);
        fwd_step<0,0>(A, B0, B1, XT[1][0], XT[1][1], XT[1][2], p0, p1, p2, Clog, bp_addr, rbp);
        fwd_step<0,1>(A, B0, B1, XT[2][0], XT[2][1], XT[2][2], p0, p1, p2, Clog, bp_addr, rbp);

        // publish q_255 and Clog_a
#pragma unroll
        for (int r = 0; r < 4; ++r) {
            xch[l * 12 + r]     = p0[r];
            xch[l * 12 + 4 + r] = p1[r];
            xch[l * 12 + 8 + r] = p2[r];
        }
        if (g == 0) xch[768 + c] = Clog;
    } else {
        // ======== BACKWARD: init u_511 = exp(trans[:,STOP]), t=511..256 ========
#pragma unroll
        for (int r = 0; r < 4; ++r) {
            p0[r] = __expf(trans[(     4 * g + r) * NST + STOP_S]);
            p1[r] = __expf(trans[(16 + 4 * g + r) * NST + STOP_S]);
            p2[r] = __expf(trans[(32 + 4 * g + r) * NST + STOP_S]);
        }
        {
            f32x4 T0[4][3];
            LOADBLKD(T0, 511)
            LOADBLKD(R0, 507)
            LOADBLKD(R1, 503)
            EXPBLK(EX, T0)
        }
        int t = 511;
        for (int d = 0; d < 32; ++d) {             // t = 511..256
            BBLK4(EX)
            EXPBLK(EX, R0)
            LOADBLKD(R0, t - 12)
            BBLK4(EX)
            EXPBLK(EX, R1)
            LOADBLKD(R1, t - 16)
            t -= 8;
        }
    }

    __syncthreads();

    if (wid == 1) {
        float s = 0.0f;
#pragma unroll
        for (int r = 0; r < 4; ++r) {
            s += xch[l * 12 + r]     * p0[r];
            s += xch[l * 12 + 4 + r] * p1[r];
            s += xch[l * 12 + 8 + r] * p2[r];
        }
        s += __shfl_xor(s, 16, 64);
        s += __shfl_xor(s, 32, 64);
        if (l < 16)
            logz_out[blockIdx.x * 16 + l] = xch[768 + l] + Clog + __logf(s);
    }
}

__global__ __launch_bounds__(64)
void crf_gold_kernel(const float* __restrict__ emissions,
                     const int*   __restrict__ tags,
                     const float* __restrict__ trans,
                     float*       __restrict__ gold_out)
{
    const int b    = blockIdx.x;
    const int lane = threadIdx.x;
    const float* em  = emissions + (size_t)b * TLEN * NTAGS;
    const int*   tbp = tags + (size_t)b * TLEN;
    float gacc = 0.0f;
#pragma unroll
    for (int k = 0; k < TLEN / 64; ++k) {
        const int tt  = k * 64 + lane;
        const int tag = tbp[tt];
        gacc += em[(size_t)tt * NTAGS + tag];
        if (tt >= 1) gacc += trans[tbp[tt - 1] * NST + tag];
    }
    gacc = wave_sum(gacc);
    if (lane == 0)
        gold_out[b] = gacc + trans[START_S * NST + tbp[0]]
                           + trans[tbp[TLEN - 1] * NST + STOP_S];
}

__global__ __launch_bounds__(256)
void crf_reduce_kernel(const float* __restrict__ logz,
                       const float* __restrict__ gold,
                       float*       __restrict__ out)
{
    __shared__ float buf[4];
    float s = 0.0f;
    for (int i = threadIdx.x; i < BATCH; i += 256) s += logz[i] - gold[i];
    s = wave_sum(s);
    const int wid = threadIdx.x >> 6;
    if ((threadIdx.x & 63) == 0) buf[wid] = s;
    __syncthreads();
    if (threadIdx.x == 0) {
        const float tot = (buf[0] + buf[1]) + (buf[2] + buf[3]);
        const float nll = tot / (float)BATCH;
        const float h_max = logf((float)NTAGS);
        out[0] = 0.9f * nll + 0.1f * h_max;
    }
}

extern "C" void kernel_launch(void* const* d_in, const int* in_sizes, int n_in,
                              void* d_out, int out_size, void* d_ws, size_t ws_size,
                              hipStream_t stream)
{
    const float* emissions = (const float*)d_in[0];
    const int*   tags      = (const int*)d_in[1];
    // d_in[2] = mask: all-ones; ignored
    const float* trans     = (const float*)d_in[3];

    if (ws_size < 2 * BATCH * sizeof(float)) return;
    float* logz = (float*)d_ws;
    float* gold = logz + BATCH;

    crf_fwdbwd<<<BATCH / 16, 128, 0, stream>>>(emissions, trans, logz);
    crf_gold_kernel<<<BATCH, 64, 0, stream>>>(emissions, tags, trans, gold);
    crf_reduce_kernel<<<1, 256, 0, stream>>>(logz, gold, (float*)d_out);
}

// Round 16
// 87.694 us; speedup vs baseline: 4.9088x; 1.2495x over previous
//
#include <hip/hip_runtime.h>
#include <hip/hip_bf16.h>
#include <math.h>

// CRF NLL on MI355X — round 16: fwd/bwd halves in SEPARATE single-wave blocks.
// r15 finding: two co-resident waves on one CU did not overlap (per-CU
// MfmaUtil flat, per-step latency doubled) — same pattern as r3. Fix + clean
// experiment: 128 blocks x 64 threads -> 128 CUs, one wave each. Blocks 0-63:
// forward t=0..255 for group bid; blocks 64-127: backward t=511..256 for group
// bid-64. Fragments + Clog published to d_ws; combine kernel does
// logz = Cf + Cb + log(q255 . u255). Also reverts r15's independent-MFMA
// experiment back to r12's verified chained form (z-init -> acc chain).
// Numerics (tau layout, pk2 pack, exact pow2 PREP/APPLY renorm) = r15, absmax 0.

#define NTAGS   48
#define NST     50
#define START_S 48
#define STOP_S  49
#define BATCH   1024
#define TLEN    512

typedef short  bf16x8 __attribute__((ext_vector_type(8)));
typedef float  f32x4  __attribute__((ext_vector_type(4)));

union B4 { unsigned u[4]; short s[8]; bf16x8 v; };

__device__ __forceinline__ short to_bf16(float f) {     // RNE, pure C
    unsigned u = __float_as_uint(f);
    unsigned r = ((u >> 16) & 1u) + 0x7FFFu;
    return (short)((u + r) >> 16);
}

__device__ __forceinline__ unsigned pk2(float lo, float hi) {  // RNE pair pack
    float2 f; f.x = lo; f.y = hi;
    __hip_bfloat162 h = __float22bfloat162_rn(f);
    union { __hip_bfloat162 h; unsigned u; } cvt; cvt.h = h;
    return cvt.u;
}

__device__ __forceinline__ float wave_sum(float v) {
#pragma unroll
    for (int off = 32; off >= 1; off >>= 1)
        v += __shfl_xor(v, off, 64);
    return v;
}

#define RENORM_APPLY                                                     \
    {   int ex = ((rbp >> 23) & 255) - 127;                              \
        ex = ex > 126 ? 126 : (ex < -126 ? -126 : ex);                   \
        float sc = __uint_as_float((unsigned)(127 - ex) << 23);          \
        p0 *= sc; p1 *= sc; p2 *= sc;                                    \
        Clog += (float)ex * 0.69314718055994531f; }

// ---- forward step (r12 chained form). MODE: 0 norm, 1 PREP, 2 APPLY.
template<int MODE, int LAST>
__device__ __forceinline__ void fwd_step(const bf16x8 (&A)[3][2],
    bf16x8 &B0, bf16x8 &B1,
    const f32x4 &X0, const f32x4 &X1, const f32x4 &X2,
    f32x4 &p0, f32x4 &p1, f32x4 &p2, float &Clog, int bp_addr, int &rbp)
{
    const f32x4 z = {0.f, 0.f, 0.f, 0.f};
    f32x4 a0 = __builtin_amdgcn_mfma_f32_16x16x32_bf16(A[0][0], B0, z, 0, 0, 0);
    a0 = __builtin_amdgcn_mfma_f32_16x16x32_bf16(A[0][1], B1, a0, 0, 0, 0);
    f32x4 a1 = __builtin_amdgcn_mfma_f32_16x16x32_bf16(A[1][0], B0, z, 0, 0, 0);
    a1 = __builtin_amdgcn_mfma_f32_16x16x32_bf16(A[1][1], B1, a1, 0, 0, 0);
    f32x4 a2 = __builtin_amdgcn_mfma_f32_16x16x32_bf16(A[2][0], B0, z, 0, 0, 0);
    a2 = __builtin_amdgcn_mfma_f32_16x16x32_bf16(A[2][1], B1, a2, 0, 0, 0);
    p0 = a0 * X0;  p1 = a1 * X1;  p2 = a2 * X2;
    if (MODE == 2) RENORM_APPLY
    if (MODE == 1) rbp = __builtin_amdgcn_ds_bpermute(bp_addr, __float_as_int(p0[0]));
    if (!LAST) {
        B4 nb0;
        nb0.u[0] = pk2(p0[0], p0[1]);  nb0.u[1] = pk2(p0[2], p0[3]);
        nb0.u[2] = pk2(p1[0], p1[1]);  nb0.u[3] = pk2(p1[2], p1[3]);
        B0 = nb0.v;
        B4 nb1;
        nb1.u[0] = pk2(p2[0], p2[1]);  nb1.u[1] = pk2(p2[2], p2[3]);
        nb1.u[2] = 0u;                 nb1.u[3] = 0u;
        B1 = nb1.v;
    }
}

// ---- backward step: u_{t-1} = W (e_t o u_t). p in/out, chained MFMAs.
template<int MODE>
__device__ __forceinline__ void bwd_step(const bf16x8 (&A)[3][2],
    const f32x4 &X0, const f32x4 &X1, const f32x4 &X2,
    f32x4 &p0, f32x4 &p1, f32x4 &p2, float &Clog, int bp_addr, int &rbp)
{
    f32x4 h0 = p0 * X0, h1 = p1 * X1, h2 = p2 * X2;
    B4 nb0;
    nb0.u[0] = pk2(h0[0], h0[1]);  nb0.u[1] = pk2(h0[2], h0[3]);
    nb0.u[2] = pk2(h1[0], h1[1]);  nb0.u[3] = pk2(h1[2], h1[3]);
    B4 nb1;
    nb1.u[0] = pk2(h2[0], h2[1]);  nb1.u[1] = pk2(h2[2], h2[3]);
    nb1.u[2] = 0u;                 nb1.u[3] = 0u;
    const bf16x8 B0 = nb0.v, B1 = nb1.v;
    const f32x4 z = {0.f, 0.f, 0.f, 0.f};
    f32x4 a0 = __builtin_amdgcn_mfma_f32_16x16x32_bf16(A[0][0], B0, z, 0, 0, 0);
    a0 = __builtin_amdgcn_mfma_f32_16x16x32_bf16(A[0][1], B1, a0, 0, 0, 0);
    f32x4 a1 = __builtin_amdgcn_mfma_f32_16x16x32_bf16(A[1][0], B0, z, 0, 0, 0);
    a1 = __builtin_amdgcn_mfma_f32_16x16x32_bf16(A[1][1], B1, a1, 0, 0, 0);
    f32x4 a2 = __builtin_amdgcn_mfma_f32_16x16x32_bf16(A[2][0], B0, z, 0, 0, 0);
    a2 = __builtin_amdgcn_mfma_f32_16x16x32_bf16(A[2][1], B1, a2, 0, 0, 0);
    p0 = a0;  p1 = a1;  p2 = a2;
    if (MODE == 2) RENORM_APPLY
    if (MODE == 1) rbp = __builtin_amdgcn_ds_bpermute(bp_addr, __float_as_int(p0[0]));
}

#define LOADBLK(R, T)                                                        \
    _Pragma("unroll") for (int u2 = 0; u2 < 4; ++u2) {                       \
        _Pragma("unroll") for (int mt = 0; mt < 3; ++mt)                     \
            R[u2][mt] = *(const f32x4*)(emg + (size_t)((T) + u2) * NTAGS + 16 * mt); \
    }
#define LOADBLKD(R, T)                                                       \
    _Pragma("unroll") for (int u2 = 0; u2 < 4; ++u2) {                       \
        _Pragma("unroll") for (int mt = 0; mt < 3; ++mt)                     \
            R[u2][mt] = *(const f32x4*)(emg + (size_t)((T) - u2) * NTAGS + 16 * mt); \
    }
#define EXPBLK(X, R)                                                         \
    _Pragma("unroll") for (int u2 = 0; u2 < 4; ++u2)                         \
        _Pragma("unroll") for (int mt = 0; mt < 3; ++mt)                     \
            _Pragma("unroll") for (int r = 0; r < 4; ++r)                    \
                X[u2][mt][r] = __expf(R[u2][mt][r]);

#define FBLK4(X)                                                             \
    fwd_step<0,0>(A, B0, B1, X[0][0], X[0][1], X[0][2], p0, p1, p2, Clog, bp_addr, rbp); \
    fwd_step<0,0>(A, B0, B1, X[1][0], X[1][1], X[1][2], p0, p1, p2, Clog, bp_addr, rbp); \
    fwd_step<1,0>(A, B0, B1, X[2][0], X[2][1], X[2][2], p0, p1, p2, Clog, bp_addr, rbp); \
    fwd_step<2,0>(A, B0, B1, X[3][0], X[3][1], X[3][2], p0, p1, p2, Clog, bp_addr, rbp);

#define BBLK4(X)                                                             \
    bwd_step<0>(A, X[0][0], X[0][1], X[0][2], p0, p1, p2, Clog, bp_addr, rbp); \
    bwd_step<0>(A, X[1][0], X[1][1], X[1][2], p0, p1, p2, Clog, bp_addr, rbp); \
    bwd_step<1>(A, X[2][0], X[2][1], X[2][2], p0, p1, p2, Clog, bp_addr, rbp); \
    bwd_step<2>(A, X[3][0], X[3][1], X[3][2], p0, p1, p2, Clog, bp_addr, rbp);

// ws layout (floats): qfrag[64][64][12] | ufrag[64][64][12] | Cf[64][16] | Cb[64][16]
#define WS_Q   0
#define WS_U   49152
#define WS_CF  98304
#define WS_CB  99328
#define WS_NEEDED_FLOATS 100352

__global__ __launch_bounds__(64)
__attribute__((amdgpu_waves_per_eu(1, 1)))
void crf_half(const float* __restrict__ emissions,  // [B, T, 48]
              const float* __restrict__ trans,      // [50, 50]
              float*       __restrict__ ws)
{
    const int bid = blockIdx.x;
    const bool is_fwd = (bid < 64);
    const int grp = is_fwd ? bid : (bid - 64);
    const int l = threadIdx.x;
    const int g = l >> 4;
    const int c = l & 15;
    const int brow = grp * 16 + c;

    // A fragments: fwd A(m,k)=exp(trans[sk][m]); bwd A(m,k)=exp(trans[m][sk])
    bf16x8 A[3][2];
#pragma unroll
    for (int mt = 0; mt < 3; ++mt)
#pragma unroll
        for (int kt = 0; kt < 2; ++kt) {
            B4 u;
#pragma unroll
            for (int e = 0; e < 8; ++e) {
                const int sk = 16 * (2 * kt + (e >> 2)) + 4 * g + (e & 3);
                const int m  = 16 * mt + c;
                float f = 0.0f;
                if (sk < NTAGS)
                    f = __expf(is_fwd ? trans[sk * NST + m] : trans[m * NST + sk]);
                u.s[e] = to_bf16(f);
            }
            A[mt][kt] = u.v;
        }
    asm volatile("" : "+v"(A[0][0]), "+v"(A[0][1]), "+v"(A[1][0]),
                      "+v"(A[1][1]), "+v"(A[2][0]), "+v"(A[2][1]));

    const float* emc = emissions + (size_t)brow * (TLEN * NTAGS);
    const float* emg = emc + 4 * g;

    const int bp_addr = c << 2;
    f32x4 p0, p1, p2;
    float Clog = 0.0f;
    int rbp = __float_as_int(1.0f);
    f32x4 EX[4][3], R0[4][3], R1[4][3];

    if (is_fwd) {
        // ---- FORWARD: init t=0; steps t=1..255 -> q_255
        bf16x8 B0, B1;
        {
            f32x4 i0 = *(const f32x4*)(emc +      4 * g);
            f32x4 i1 = *(const f32x4*)(emc + 16 + 4 * g);
            f32x4 i2 = *(const f32x4*)(emc + 32 + 4 * g);
            B4 nb0, nb1;
#pragma unroll
            for (int r = 0; r < 4; ++r) {
                nb0.s[r]     = to_bf16(__expf(trans[START_S * NST +      4 * g + r] + i0[r]));
                nb0.s[4 + r] = to_bf16(__expf(trans[START_S * NST + 16 + 4 * g + r] + i1[r]));
                nb1.s[r]     = to_bf16(__expf(trans[START_S * NST + 32 + 4 * g + r] + i2[r]));
            }
            nb1.u[2] = 0u;  nb1.u[3] = 0u;
            B0 = nb0.v;  B1 = nb1.v;
        }
        {
            f32x4 T0[4][3];
            LOADBLK(T0, 1)
            LOADBLK(R0, 5)
            LOADBLK(R1, 9)
            EXPBLK(EX, T0)
        }
        int t = 1;
        for (int d = 0; d < 31; ++d) {             // t = 1..248
            FBLK4(EX)
            EXPBLK(EX, R0)
            LOADBLK(R0, t + 12)
            FBLK4(EX)
            EXPBLK(EX, R1)
            LOADBLK(R1, t + 16)
            t += 8;
        }
        FBLK4(EX)                                   // 249..252
        f32x4 XT[3][3];
#pragma unroll
        for (int u2 = 0; u2 < 3; ++u2)
#pragma unroll
            for (int mt = 0; mt < 3; ++mt)
#pragma unroll
                for (int r = 0; r < 4; ++r)
                    XT[u2][mt][r] = __expf(R0[u2][mt][r]);
        fwd_step<0,0>(A, B0, B1, XT[0][0], XT[0][1], XT[0][2], p0, p1, p2, Clog, bp_addr, rbp);
        fwd_step<0,0>(A, B0, B1, XT[1][0], XT[1][1], XT[1][2], p0, p1, p2, Clog, bp_addr, rbp);
        fwd_step<0,1>(A, B0, B1, XT[2][0], XT[2][1], XT[2][2], p0, p1, p2, Clog, bp_addr, rbp);

        float* q = ws + WS_Q + (size_t)grp * 768 + l * 12;
#pragma unroll
        for (int r = 0; r < 4; ++r) {
            q[r] = p0[r];  q[4 + r] = p1[r];  q[8 + r] = p2[r];
        }
        if (g == 0) ws[WS_CF + grp * 16 + c] = Clog;
    } else {
        // ---- BACKWARD: init u_511 = exp(trans[:,STOP]); t=511..256 -> u_255
#pragma unroll
        for (int r = 0; r < 4; ++r) {
            p0[r] = __expf(trans[(     4 * g + r) * NST + STOP_S]);
            p1[r] = __expf(trans[(16 + 4 * g + r) * NST + STOP_S]);
            p2[r] = __expf(trans[(32 + 4 * g + r) * NST + STOP_S]);
        }
        {
            f32x4 T0[4][3];
            LOADBLKD(T0, 511)
            LOADBLKD(R0, 507)
            LOADBLKD(R1, 503)
            EXPBLK(EX, T0)
        }
        int t = 511;
        for (int d = 0; d < 32; ++d) {             // t = 511..256
            BBLK4(EX)
            EXPBLK(EX, R0)
            LOADBLKD(R0, t - 12)
            BBLK4(EX)
            EXPBLK(EX, R1)
            LOADBLKD(R1, t - 16)
            t -= 8;
        }
        float* u = ws + WS_U + (size_t)grp * 768 + l * 12;
#pragma unroll
        for (int r = 0; r < 4; ++r) {
            u[r] = p0[r];  u[4 + r] = p1[r];  u[8 + r] = p2[r];
        }
        if (g == 0) ws[WS_CB + grp * 16 + c] = Clog;
    }
}

__global__ __launch_bounds__(64)
void crf_combine(const float* __restrict__ ws, float* __restrict__ logz_out)
{
    const int grp = blockIdx.x;
    const int l = threadIdx.x;
    const float* q = ws + WS_Q + (size_t)grp * 768 + l * 12;
    const float* u = ws + WS_U + (size_t)grp * 768 + l * 12;
    float s = 0.0f;
#pragma unroll
    for (int k = 0; k < 12; ++k) s += q[k] * u[k];
    s += __shfl_xor(s, 16, 64);
    s += __shfl_xor(s, 32, 64);
    if (l < 16)
        logz_out[grp * 16 + l] = ws[WS_CF + grp * 16 + l]
                               + ws[WS_CB + grp * 16 + l] + __logf(s);
}

__global__ __launch_bounds__(64)
void crf_gold_kernel(const float* __restrict__ emissions,
                     const int*   __restrict__ tags,
                     const float* __restrict__ trans,
                     float*       __restrict__ gold_out)
{
    const int b    = blockIdx.x;
    const int lane = threadIdx.x;
    const float* em  = emissions + (size_t)b * TLEN * NTAGS;
    const int*   tbp = tags + (size_t)b * TLEN;
    float gacc = 0.0f;
#pragma unroll
    for (int k = 0; k < TLEN / 64; ++k) {
        const int tt  = k * 64 + lane;
        const int tag = tbp[tt];
        gacc += em[(size_t)tt * NTAGS + tag];
        if (tt >= 1) gacc += trans[tbp[tt - 1] * NST + tag];
    }
    gacc = wave_sum(gacc);
    if (lane == 0)
        gold_out[b] = gacc + trans[START_S * NST + tbp[0]]
                           + trans[tbp[TLEN - 1] * NST + STOP_S];
}

__global__ __launch_bounds__(256)
void crf_reduce_kernel(const float* __restrict__ logz,
                       const float* __restrict__ gold,
                       float*       __restrict__ out)
{
    __shared__ float buf[4];
    float s = 0.0f;
    for (int i = threadIdx.x; i < BATCH; i += 256) s += logz[i] - gold[i];
    s = wave_sum(s);
    const int wid = threadIdx.x >> 6;
    if ((threadIdx.x & 63) == 0) buf[wid] = s;
    __syncthreads();
    if (threadIdx.x == 0) {
        const float tot = (buf[0] + buf[1]) + (buf[2] + buf[3]);
        const float nll = tot / (float)BATCH;
        const float h_max = logf((float)NTAGS);
        out[0] = 0.9f * nll + 0.1f * h_max;
    }
}

extern "C" void kernel_launch(void* const* d_in, const int* in_sizes, int n_in,
                              void* d_out, int out_size, void* d_ws, size_t ws_size,
                              hipStream_t stream)
{
    const float* emissions = (const float*)d_in[0];
    const int*   tags      = (const int*)d_in[1];
    // d_in[2] = mask: all-ones; ignored
    const float* trans     = (const float*)d_in[3];

    // floats: frags+C (100352) + logz (1024) + gold (1024)
    if (ws_size < (WS_NEEDED_FLOATS + 2 * BATCH) * sizeof(float)) return;
    float* ws   = (float*)d_ws;
    float* logz = ws + WS_NEEDED_FLOATS;
    float* gold = logz + BATCH;

    crf_half<<<128, 64, 0, stream>>>(emissions, trans, ws);
    crf_gold_kernel<<<BATCH, 64, 0, stream>>>(emissions, tags, trans, gold);
    crf_combine<<<64, 64, 0, stream>>>(ws, logz);
    crf_reduce_kernel<<<1, 256, 0, stream>>>(logz, gold, (float*)d_out);
}